// Round 1
// baseline (388.122 us; speedup 1.0000x reference)
//
#include <hip/hip_runtime.h>

typedef unsigned short u16;
typedef unsigned int   u32;
typedef __attribute__((ext_vector_type(8))) short bf16x8;
typedef __attribute__((ext_vector_type(4))) float f32x4;

#define NV 110592          // 48*48*48
#define T_TILES 3          // 64-voxel tiles per block
#define NIT (T_TILES*6)

#define OFF_A  0u
#define OFF_MM (96u*NV)
#define OFF_MK (384u*NV)
#define OFF_FM (480u*NV)
#define OFF_FK (516u*NV)

__device__ __forceinline__ u16 f2bf(float f) {
  u32 u = __float_as_uint(f);
  u += 0x7FFFu + ((u >> 16) & 1u);   // RNE
  return (u16)(u >> 16);
}
__device__ __forceinline__ float silu_f(float x) {
  float s = __builtin_amdgcn_rcpf(1.0f + __builtin_amdgcn_exp2f(-1.44269504089f * x));
  return x * s;
}
__device__ __forceinline__ float softplus_f(float x) {
  float e = __builtin_amdgcn_exp2f(-1.44269504089f * fabsf(x));
  return fmaxf(x, 0.0f) + 0.69314718056f * __builtin_amdgcn_logf(1.0f + e);
}
// channel-slot permutation making D-frags (groups of 4) == next B-frags (groups of 8)
__device__ __forceinline__ int chmap(int r, int m) {
  return ((r >> 1) << 5) + ((m >> 2) << 3) + ((r & 1) << 2) + (m & 3);
}

// ---------------- weight fragment packing (runs every launch; d_ws is re-poisoned) --------
__global__ void pack_weights(const float* __restrict__ W1, const float* __restrict__ b1,
                             const float* __restrict__ W2, const float* __restrict__ b2,
                             const float* __restrict__ W3, const float* __restrict__ b3,
                             u16* __restrict__ wsA, float* __restrict__ wsB)
{
  const int l  = threadIdx.x;       // 0..63 (lane)
  const int m  = l & 15;            // A-row within 16-tile
  const int hq = l >> 4;            // K-quarter
  const int f  = blockIdx.x;

  if (f < 4) {                       // A1 frags, rowtile r=f, K=32 (26 real + bias@26)
    const int row = chmap(f, m);
    #pragma unroll
    for (int j = 0; j < 8; ++j) {
      const int k = hq * 8 + j;
      float v = (k < 26) ? W1[row * 26 + k] : ((k == 26) ? b1[row] : 0.0f);
      wsA[(f * 64 + l) * 8 + j] = f2bf(v);
    }
  } else if (f < 12) {               // A2 frags: f = 4 + r*2 + t
    const int r = (f - 4) >> 1, t = (f - 4) & 1;
    const int row = chmap(r, m);
    #pragma unroll
    for (int j = 0; j < 8; ++j) {
      const int k = t * 32 + hq * 8 + j;
      wsA[(f * 64 + l) * 8 + j] = f2bf(W2[row * 64 + k]);
    }
  } else if (f < 18) {               // A3 frags: f = 12 + r*2 + t, rows >=44 are zero-pad
    const int r = (f - 12) >> 1, t = (f - 12) & 1;
    const int row = r * 16 + m;
    #pragma unroll
    for (int j = 0; j < 8; ++j) {
      const int k = t * 32 + hq * 8 + j;
      float v = (row < 44) ? W3[row * 64 + k] : 0.0f;
      wsA[(f * 64 + l) * 8 + j] = f2bf(v);
    }
  } else if (f == 18) {              // b2 acc-init values per lane
    #pragma unroll
    for (int s = 0; s < 16; ++s) {
      const int r = s >> 2, jj = s & 3;
      wsB[s * 64 + l] = b2[chmap(r, hq * 4 + jj)];
    }
  } else {                           // b3 acc-init values per lane
    #pragma unroll
    for (int s = 0; s < 12; ++s) {
      const int r = s >> 2, jj = s & 3;
      const int o = r * 16 + hq * 4 + jj;
      wsB[(16 + s) * 64 + l] = (o < 44) ? b3[o] : 0.0f;
    }
  }
}

// ---------------- input gather ----------------
__device__ __forceinline__ float gather_ch(int c, int face, int b,
    const float* __restrict__ counts, const float* __restrict__ momentum,
    const float* __restrict__ ke, const float* __restrict__ order,
    int sv, int dv, bool dvalid)
{
  if (c >= 26) return (c == 26) ? 1.0f : 0.0f;   // ch26 = bias input, 27..31 = pad
  const bool isd  = (c >= 13);
  const int  bc   = isd ? c - 13 : c;
  const int  vox  = isd ? dv : sv;
  const bool valid = isd ? dvalid : true;
  float sgn = 1.0f;
  const float* p;
  if (bc < 8) {
    p = counts + ((size_t)b * 8 + bc) * NV;
  } else if (bc < 11) {
    const int rr = bc - 8;
    const int pm = (rr == 0) ? (face >> 1)
                 : ((rr == 1) ? ((face < 2) ? 1 : 0) : ((face < 4) ? 2 : 1));
    if (rr == 0 && (face & 1)) sgn = -1.0f;
    p = momentum + ((size_t)b * 3 + pm) * NV;
  } else if (bc == 11) {
    p = ke + (size_t)b * NV;
  } else {
    p = order + (size_t)b * NV;
  }
  float v = p[valid ? vox : 0];
  return valid ? v * sgn : 0.0f;
}

__device__ __forceinline__ void do_stage(int it, int tile0, int b,
    const float* __restrict__ counts, const float* __restrict__ momentum,
    const float* __restrict__ ke, const float* __restrict__ order,
    u16* __restrict__ xsbuf)
{
  const int tid = threadIdx.x;
  const int ln = tid & 63, wv = tid >> 6;
  const int face = it % 6;
  const int v_lin = (tile0 + it / 6) * 64 + ln;
  const int z  = v_lin % 48;
  const int rr = v_lin / 48;
  const int y  = rr % 48;
  const int x  = rr / 48;
  int dv; bool dvalid = true;
  if      (face == 0) dv = (x == 47) ? v_lin - 108288 : v_lin + 2304;  // +x, wrap
  else if (face == 1) dv = (x == 0)  ? v_lin + 108288 : v_lin - 2304;  // -x, wrap
  else if (face == 2) dv = (y == 47) ? v_lin - 2256   : v_lin + 48;    // +y, wrap
  else if (face == 3) dv = (y == 0)  ? v_lin + 2256   : v_lin - 48;    // -y, wrap
  else if (face == 4) { dv = v_lin + 1; dvalid = (z != 47); }          // +z, zero pad
  else                { dv = v_lin - 1; dvalid = (z != 0);  }          // -z, zero pad

  u32 pk[4];
  #pragma unroll
  for (int i = 0; i < 4; ++i) {
    float f0 = gather_ch(wv * 8 + 2*i,     face, b, counts, momentum, ke, order, v_lin, dv, dvalid);
    float f1 = gather_ch(wv * 8 + 2*i + 1, face, b, counts, momentum, ke, order, v_lin, dv, dvalid);
    pk[i] = (u32)f2bf(f0) | ((u32)f2bf(f1) << 16);
  }
  // row stride 40 u16 = 80B (16B aligned blocks, bank-rotating)
  *(uint4*)(xsbuf + ln * 40 + wv * 8) = make_uint4(pk[0], pk[1], pk[2], pk[3]);
}

// ---------------- main fused kernel ----------------
__global__ __launch_bounds__(256, 2) void fused_mlp(
    const float* __restrict__ counts, const float* __restrict__ momentum,
    const float* __restrict__ ke, const float* __restrict__ order,
    const u16* __restrict__ wsA, const float* __restrict__ wsB,
    float* __restrict__ out)
{
  __shared__ u16 xs[2][64 * 40];
  const int tid = threadIdx.x;
  const int ln  = tid & 63;
  const int wv  = tid >> 6;
  const int q   = ln >> 4;
  const int nn  = ln & 15;
  const int b   = blockIdx.y;
  const int tile0 = blockIdx.x * T_TILES;

  // resident weight fragments (coalesced 16B loads)
  const bf16x8* wsAf = (const bf16x8*)wsA;
  bf16x8 A1[4], A2[4][2], A3[3][2];
  #pragma unroll
  for (int r = 0; r < 4; ++r) A1[r] = wsAf[r * 64 + ln];
  #pragma unroll
  for (int r = 0; r < 4; ++r)
    #pragma unroll
    for (int t = 0; t < 2; ++t) A2[r][t] = wsAf[(4 + r * 2 + t) * 64 + ln];
  #pragma unroll
  for (int r = 0; r < 3; ++r)
    #pragma unroll
    for (int t = 0; t < 2; ++t) A3[r][t] = wsAf[(12 + r * 2 + t) * 64 + ln];

  float b2v[16], b3v[12];
  #pragma unroll
  for (int s = 0; s < 16; ++s) b2v[s] = wsB[s * 64 + ln];
  #pragma unroll
  for (int s = 0; s < 12; ++s) b3v[s] = wsB[(16 + s) * 64 + ln];

  // per-lane output-slot addressing (constant across faces/tiles)
  u32 cb[12], fsv[12];
  u32 spmask = 0, vmask = 0;
  #pragma unroll
  for (int r3 = 0; r3 < 3; ++r3) {
    #pragma unroll
    for (int jj = 0; jj < 4; ++jj) {
      const int slot = r3 * 4 + jj;
      const int o = r3 * 16 + q * 4 + jj;
      u32 c0 = 0, f0 = 0; bool sp = false, va = true;
      if (o < 3)       { c0 = OFF_FM + (u32)o * NV;        f0 = 3u * NV; }
      else if (o == 3) { c0 = OFF_FK;                      f0 = 1u * NV; sp = true; }
      else if (o < 12) { c0 = OFF_A  + (u32)(o - 4) * NV;  f0 = 8u * NV; sp = true; }
      else if (o < 36) { c0 = OFF_MM + (u32)(o - 12) * NV; f0 = 24u * NV; }
      else if (o < 44) { c0 = OFF_MK + (u32)(o - 36) * NV; f0 = 8u * NV; sp = true; }
      else va = false;
      cb[slot] = c0; fsv[slot] = f0;
      if (sp) spmask |= (1u << slot);
      if (va) vmask  |= (1u << slot);
    }
  }

  do_stage(0, tile0, b, counts, momentum, ke, order, xs[0]);

  #pragma unroll 1
  for (int it = 0; it < NIT; ++it) {
    __syncthreads();
    if (it + 1 < NIT)
      do_stage(it + 1, tile0, b, counts, momentum, ke, order, xs[(it + 1) & 1]);

    const int face  = it % 6;
    const int vbase = (tile0 + it / 6) * 64;
    const u16* xrow = &xs[it & 1][(wv * 16 + nn) * 40];
    bf16x8 B1 = *(const bf16x8*)(xrow + q * 8);

    const f32x4 zf = {0.0f, 0.0f, 0.0f, 0.0f};
    f32x4 acc1[4];
    #pragma unroll
    for (int r = 0; r < 4; ++r)
      acc1[r] = __builtin_amdgcn_mfma_f32_16x16x32_bf16(A1[r], B1, zf, 0, 0, 0);

    bf16x8 B2f[2];
    #pragma unroll
    for (int t = 0; t < 2; ++t)
      #pragma unroll
      for (int j = 0; j < 8; ++j)
        B2f[t][j] = (short)f2bf(silu_f(acc1[t * 2 + (j >> 2)][j & 3]));

    f32x4 acc2[4];
    #pragma unroll
    for (int r = 0; r < 4; ++r) {
      f32x4 ci = {b2v[4*r+0], b2v[4*r+1], b2v[4*r+2], b2v[4*r+3]};
      acc2[r] = __builtin_amdgcn_mfma_f32_16x16x32_bf16(A2[r][0], B2f[0], ci, 0, 0, 0);
      acc2[r] = __builtin_amdgcn_mfma_f32_16x16x32_bf16(A2[r][1], B2f[1], acc2[r], 0, 0, 0);
    }

    bf16x8 B3f[2];
    #pragma unroll
    for (int t = 0; t < 2; ++t)
      #pragma unroll
      for (int j = 0; j < 8; ++j)
        B3f[t][j] = (short)f2bf(silu_f(acc2[t * 2 + (j >> 2)][j & 3]));

    f32x4 acc3[3];
    #pragma unroll
    for (int r = 0; r < 3; ++r) {
      f32x4 ci = {b3v[4*r+0], b3v[4*r+1], b3v[4*r+2], b3v[4*r+3]};
      acc3[r] = __builtin_amdgcn_mfma_f32_16x16x32_bf16(A3[r][0], B3f[0], ci, 0, 0, 0);
      acc3[r] = __builtin_amdgcn_mfma_f32_16x16x32_bf16(A3[r][1], B3f[1], acc3[r], 0, 0, 0);
    }

    const u32 b6f = (u32)(b * 6 + face);
    const u32 vg  = (u32)vbase + (u32)(wv * 16 + nn);
    #pragma unroll
    for (int r3 = 0; r3 < 3; ++r3) {
      #pragma unroll
      for (int jj = 0; jj < 4; ++jj) {
        const int slot = r3 * 4 + jj;
        float val = acc3[r3][jj];
        float res = ((spmask >> slot) & 1u) ? softplus_f(val) : val;
        if ((vmask >> slot) & 1u)
          out[cb[slot] + b6f * fsv[slot] + vg] = res;
      }
    }
  }
}

extern "C" void kernel_launch(void* const* d_in, const int* in_sizes, int n_in,
                              void* d_out, int out_size, void* d_ws, size_t ws_size,
                              hipStream_t stream)
{
  const float* counts   = (const float*)d_in[0];
  const float* momentum = (const float*)d_in[1];
  const float* ke       = (const float*)d_in[2];
  const float* order    = (const float*)d_in[3];
  const float* W1 = (const float*)d_in[4];
  const float* b1 = (const float*)d_in[5];
  const float* W2 = (const float*)d_in[6];
  const float* b2 = (const float*)d_in[7];
  const float* W3 = (const float*)d_in[8];
  const float* b3 = (const float*)d_in[9];

  u16*   wsA = (u16*)d_ws;
  float* wsB = (float*)((char*)d_ws + 18 * 64 * 8 * sizeof(u16));  // +18432 B

  pack_weights<<<dim3(20), dim3(64), 0, stream>>>(W1, b1, W2, b2, W3, b3, wsA, wsB);
  fused_mlp<<<dim3(576, 2), dim3(256), 0, stream>>>(counts, momentum, ke, order,
                                                    wsA, wsB, (float*)d_out);
}

// Round 3
// 309.001 us; speedup vs baseline: 1.2561x; 1.2561x over previous
//
#include <hip/hip_runtime.h>

typedef unsigned short u16;
typedef unsigned int   u32;
typedef __attribute__((ext_vector_type(8))) short bf16x8;
typedef __attribute__((ext_vector_type(4))) float f32x4;
typedef union { u32 w[4]; bf16x8 v; } bfpack;

#define NV 110592          // 48*48*48

#define OFF_A  0u
#define OFF_MM (96u*NV)
#define OFF_MK (384u*NV)
#define OFF_FM (480u*NV)
#define OFF_FK (516u*NV)

__device__ __forceinline__ u16 f2bf(float f) {
  u32 u = __float_as_uint(f);
  u += 0x7FFFu + ((u >> 16) & 1u);   // RNE
  return (u16)(u >> 16);
}
__device__ __forceinline__ u32 cvtpk(float a, float b) {
  u32 r; asm("v_cvt_pk_bf16_f32 %0, %1, %2" : "=v"(r) : "v"(a), "v"(b)); return r;
}
__device__ __forceinline__ float silu_f(float x) {
  float s = __builtin_amdgcn_rcpf(1.0f + __builtin_amdgcn_exp2f(-1.44269504089f * x));
  return x * s;
}
__device__ __forceinline__ float softplus_f(float x) {
  float e = __builtin_amdgcn_exp2f(-1.44269504089f * fabsf(x));
  return fmaxf(x, 0.0f) + 0.69314718056f * __builtin_amdgcn_logf(1.0f + e);
}
// channel-slot permutation making D-frags (groups of 4) == next B-frags (groups of 8)
__device__ __forceinline__ int chmap(int r, int m) {
  return ((r >> 1) << 5) + ((m >> 2) << 3) + ((r & 1) << 2) + (m & 3);
}

// ---------------- weight fragment packing (runs every launch; d_ws re-poisoned) ----
// wsA frags: [0..23]  A1 per face: idx = face*4 + rowtile   (rotation folded in)
//            [24..31] A2: idx = 24 + r*2 + t
//            [32..37] A3: idx = 32 + r*2 + t
// wsB: [0..15] b2 per-lane, [16..27] b3 per-lane
// K-slot map (face-invariant input layout):
//   k0..7  src counts     k8..10 src mom RAW   k11 ke  k12 order  k13 bias=1  k14..15 0
//   k16..23 dst counts    k24..26 dst mom RAW  k27 ke  k28 order  k29..31 0
__global__ void pack_weights(const float* __restrict__ W1, const float* __restrict__ b1,
                             const float* __restrict__ W2, const float* __restrict__ b2,
                             const float* __restrict__ W3, const float* __restrict__ b3,
                             u16* __restrict__ wsA, float* __restrict__ wsB)
{
  const int l  = threadIdx.x;       // 0..63
  const int m  = l & 15;
  const int hq = l >> 4;
  const int f  = blockIdx.x;

  if (f < 24) {                      // A1 for face
    const int face = f >> 2, r = f & 3;
    const int row  = chmap(r, m);
    // rot slot/sign tables: raw component cm maps to rotated slot with sign
    const int   slot_tbl[6][3] = {{0,1,2},{0,1,2},{1,0,2},{1,0,2},{1,2,0},{1,2,0}};
    const float sign_tbl[6][3] = {{1,1,1},{-1,1,1},{1,1,1},{1,-1,1},{1,1,1},{1,1,-1}};
    #pragma unroll
    for (int j = 0; j < 8; ++j) {
      const int k = hq * 8 + j;
      float v;
      if      (k < 8)   v = W1[row * 26 + k];
      else if (k < 11)  { int cm = k - 8;  v = sign_tbl[face][cm] * W1[row * 26 + 8  + slot_tbl[face][cm]]; }
      else if (k == 11) v = W1[row * 26 + 11];
      else if (k == 12) v = W1[row * 26 + 12];
      else if (k == 13) v = b1[row];
      else if (k < 16)  v = 0.0f;
      else if (k < 24)  v = W1[row * 26 + 13 + (k - 16)];
      else if (k < 27)  { int cm = k - 24; v = sign_tbl[face][cm] * W1[row * 26 + 21 + slot_tbl[face][cm]]; }
      else if (k == 27) v = W1[row * 26 + 24];
      else if (k == 28) v = W1[row * 26 + 25];
      else              v = 0.0f;
      wsA[(f * 64 + l) * 8 + j] = f2bf(v);
    }
  } else if (f < 32) {               // A2
    const int r = (f - 24) >> 1, t = (f - 24) & 1;
    const int row = chmap(r, m);
    #pragma unroll
    for (int j = 0; j < 8; ++j) {
      const int k = t * 32 + hq * 8 + j;
      wsA[(f * 64 + l) * 8 + j] = f2bf(W2[row * 64 + k]);
    }
  } else if (f < 38) {               // A3 (rows >=44 zero)
    const int r = (f - 32) >> 1, t = (f - 32) & 1;
    const int row = r * 16 + m;
    #pragma unroll
    for (int j = 0; j < 8; ++j) {
      const int k = t * 32 + hq * 8 + j;
      float v = (row < 44) ? W3[row * 64 + k] : 0.0f;
      wsA[(f * 64 + l) * 8 + j] = f2bf(v);
    }
  } else if (f == 38) {              // b2 acc-init per lane
    #pragma unroll
    for (int s = 0; s < 16; ++s) {
      const int r = s >> 2, jj = s & 3;
      wsB[s * 64 + l] = b2[chmap(r, hq * 4 + jj)];
    }
  } else {                           // b3 acc-init per lane
    #pragma unroll
    for (int s = 0; s < 12; ++s) {
      const int r = s >> 2, jj = s & 3;
      const int o = r * 16 + hq * 4 + jj;
      wsB[(16 + s) * 64 + l] = (o < 44) ? b3[o] : 0.0f;
    }
  }
}

// ---------------- main fused kernel ----------------
// block = 256 threads; one 64-voxel tile per block; 6 faces inner (fully unrolled).
// LDS row per voxel: 40 u16 (80B, 16B-aligned): [0..15]=src half, [16..31]=dst half.
// src half written once per tile (both buffers); dst half double-buffered per face.
__global__ __launch_bounds__(256, 2) void fused_mlp(
    const float* __restrict__ counts, const float* __restrict__ momentum,
    const float* __restrict__ ke, const float* __restrict__ order,
    const u16* __restrict__ wsA, const float* __restrict__ wsB,
    float* __restrict__ out)
{
  __shared__ u16 xs[2][64 * 40];
  const int tid = threadIdx.x;
  const int ln  = tid & 63;
  const int wv  = tid >> 6;
  const int q   = ln >> 4;
  const int nn  = ln & 15;
  const int b   = blockIdx.y;
  const int vbase = blockIdx.x * 64;
  const int v   = vbase + ln;

  // voxel coords + per-face neighbor offsets (once per block)
  const int z = v % 48;
  const int rr = v / 48;
  const int y = rr % 48;
  const int x = rr / 48;
  int dvs[6];
  dvs[0] = v + ((x == 47) ? -108288 : 2304);
  dvs[1] = v + ((x == 0)  ?  108288 : -2304);
  dvs[2] = v + ((y == 47) ? -2256   : 48);
  dvs[3] = v + ((y == 0)  ?  2256   : -48);
  dvs[4] = v + 1;
  dvs[5] = v - 1;
  const bool val4 = (z != 47), val5 = (z != 0);

  // per-wave channel pointers: this wave stages channels c = 4*wv + i (raw layout)
  const float* dchp[4];
  #pragma unroll
  for (int i = 0; i < 4; ++i) {
    const int c = 4 * wv + i;
    const float* p = nullptr;
    if      (c < 8)   p = counts   + ((size_t)b * 8 + c) * NV;
    else if (c < 11)  p = momentum + ((size_t)b * 3 + (c - 8)) * NV;
    else if (c == 11) p = ke    + (size_t)b * NV;
    else if (c == 12) p = order + (size_t)b * NV;
    dchp[i] = p;
  }

  // resident weights
  const bf16x8* wsAf = (const bf16x8*)wsA;
  bf16x8 A2[4][2], A3[3][2];
  #pragma unroll
  for (int r = 0; r < 4; ++r)
    #pragma unroll
    for (int t = 0; t < 2; ++t) A2[r][t] = wsAf[(24 + r * 2 + t) * 64 + ln];
  #pragma unroll
  for (int r = 0; r < 3; ++r)
    #pragma unroll
    for (int t = 0; t < 2; ++t) A3[r][t] = wsAf[(32 + r * 2 + t) * 64 + ln];
  float b2v[16], b3v[12];
  #pragma unroll
  for (int s = 0; s < 16; ++s) b2v[s] = wsB[s * 64 + ln];
  #pragma unroll
  for (int s = 0; s < 12; ++s) b3v[s] = wsB[(16 + s) * 64 + ln];

  // A1 double buffer: prefetch face 0
  bf16x8 A1buf[2][4];
  #pragma unroll
  for (int r = 0; r < 4; ++r) A1buf[0][r] = wsAf[r * 64 + ln];

  // per-lane output-slot addressing (constant across faces)
  u32 cb[12], fsv[12];
  u32 spmask = 0, vmask = 0;
  #pragma unroll
  for (int r3 = 0; r3 < 3; ++r3) {
    #pragma unroll
    for (int jj = 0; jj < 4; ++jj) {
      const int slot = r3 * 4 + jj;
      const int o = r3 * 16 + q * 4 + jj;
      u32 c0 = 0, f0 = 0; bool sp = false, va = true;
      if (o < 3)       { c0 = OFF_FM + (u32)o * NV;        f0 = 3u * NV; }
      else if (o == 3) { c0 = OFF_FK;                      f0 = 1u * NV; sp = true; }
      else if (o < 12) { c0 = OFF_A  + (u32)(o - 4) * NV;  f0 = 8u * NV; sp = true; }
      else if (o < 36) { c0 = OFF_MM + (u32)(o - 12) * NV; f0 = 24u * NV; }
      else if (o < 44) { c0 = OFF_MK + (u32)(o - 36) * NV; f0 = 8u * NV; sp = true; }
      else va = false;
      cb[slot] = c0; fsv[slot] = f0;
      if (sp) spmask |= (1u << slot);
      if (va) vmask  |= (1u << slot);
    }
  }

  // ---- src half: staged once (face-invariant, raw momentum), both buffers ----
  {
    float sv[4];
    #pragma unroll
    for (int i = 0; i < 4; ++i) {
      const int k = 4 * wv + i;
      sv[i] = dchp[i] ? dchp[i][v] : ((k == 13) ? 1.0f : 0.0f);
    }
    const uint2 pk = make_uint2(cvtpk(sv[0], sv[1]), cvtpk(sv[2], sv[3]));
    *(uint2*)(&xs[0][ln * 40 + wv * 4]) = pk;
    *(uint2*)(&xs[1][ln * 40 + wv * 4]) = pk;
  }
  // ---- dst half for face 0 (always valid: x wraps) ----
  {
    float d0[4];
    #pragma unroll
    for (int i = 0; i < 4; ++i) d0[i] = dchp[i] ? dchp[i][dvs[0]] : 0.0f;
    *(uint2*)(&xs[0][ln * 40 + 16 + wv * 4]) =
        make_uint2(cvtpk(d0[0], d0[1]), cvtpk(d0[2], d0[3]));
  }

  __syncthreads();

  const u32 vg = (u32)(vbase + wv * 16 + nn);
  const u32 b6 = (u32)(b * 6);

  #pragma unroll
  for (int f = 0; f < 6; ++f) {
    // 1) issue next-face dst loads into regs (latency hides under compute)
    float ndv[4] = {0.0f, 0.0f, 0.0f, 0.0f};
    if (f < 5) {
      const int nf = f + 1;
      const bool nval = (nf == 4) ? val4 : ((nf == 5) ? val5 : true);
      #pragma unroll
      for (int i = 0; i < 4; ++i)
        if (dchp[i] && nval) ndv[i] = dchp[i][dvs[nf]];
    }
    // 2) prefetch next face's A1 frags
    if (f < 5) {
      #pragma unroll
      for (int r = 0; r < 4; ++r)
        A1buf[(f + 1) & 1][r] = wsAf[((f + 1) * 4 + r) * 64 + ln];
    }

    // 3) compute from current buffer
    const u16* xrow = &xs[f & 1][(wv * 16 + nn) * 40];
    const bf16x8 B1 = *(const bf16x8*)(xrow + q * 8);

    const f32x4 zf = {0.0f, 0.0f, 0.0f, 0.0f};
    f32x4 acc1[4];
    #pragma unroll
    for (int r = 0; r < 4; ++r)
      acc1[r] = __builtin_amdgcn_mfma_f32_16x16x32_bf16(A1buf[f & 1][r], B1, zf, 0, 0, 0);

    bfpack B2p[2];
    #pragma unroll
    for (int t = 0; t < 2; ++t) {
      B2p[t].w[0] = cvtpk(silu_f(acc1[t*2][0]),   silu_f(acc1[t*2][1]));
      B2p[t].w[1] = cvtpk(silu_f(acc1[t*2][2]),   silu_f(acc1[t*2][3]));
      B2p[t].w[2] = cvtpk(silu_f(acc1[t*2+1][0]), silu_f(acc1[t*2+1][1]));
      B2p[t].w[3] = cvtpk(silu_f(acc1[t*2+1][2]), silu_f(acc1[t*2+1][3]));
    }

    f32x4 acc2[4];
    #pragma unroll
    for (int r = 0; r < 4; ++r) {
      f32x4 ci = {b2v[4*r+0], b2v[4*r+1], b2v[4*r+2], b2v[4*r+3]};
      acc2[r] = __builtin_amdgcn_mfma_f32_16x16x32_bf16(A2[r][0], B2p[0].v, ci, 0, 0, 0);
      acc2[r] = __builtin_amdgcn_mfma_f32_16x16x32_bf16(A2[r][1], B2p[1].v, acc2[r], 0, 0, 0);
    }

    bfpack B3p[2];
    #pragma unroll
    for (int t = 0; t < 2; ++t) {
      B3p[t].w[0] = cvtpk(silu_f(acc2[t*2][0]),   silu_f(acc2[t*2][1]));
      B3p[t].w[1] = cvtpk(silu_f(acc2[t*2][2]),   silu_f(acc2[t*2][3]));
      B3p[t].w[2] = cvtpk(silu_f(acc2[t*2+1][0]), silu_f(acc2[t*2+1][1]));
      B3p[t].w[3] = cvtpk(silu_f(acc2[t*2+1][2]), silu_f(acc2[t*2+1][3]));
    }

    f32x4 acc3[3];
    #pragma unroll
    for (int r = 0; r < 3; ++r) {
      f32x4 ci = {b3v[4*r+0], b3v[4*r+1], b3v[4*r+2], b3v[4*r+3]};
      acc3[r] = __builtin_amdgcn_mfma_f32_16x16x32_bf16(A3[r][0], B3p[0].v, ci, 0, 0, 0);
      acc3[r] = __builtin_amdgcn_mfma_f32_16x16x32_bf16(A3[r][1], B3p[1].v, acc3[r], 0, 0, 0);
    }

    // 4) epilogue + stores
    const u32 b6f = b6 + (u32)f;
    #pragma unroll
    for (int r3 = 0; r3 < 3; ++r3) {
      #pragma unroll
      for (int jj = 0; jj < 4; ++jj) {
        const int slot = r3 * 4 + jj;
        float val = acc3[r3][jj];
        float res = ((spmask >> slot) & 1u) ? softplus_f(val) : val;
        if ((vmask >> slot) & 1u)
          out[cb[slot] + b6f * fsv[slot] + vg] = res;
      }
    }

    // 5) write next-face dst half into the other buffer
    if (f < 5) {
      *(uint2*)(&xs[(f + 1) & 1][ln * 40 + 16 + wv * 4]) =
          make_uint2(cvtpk(ndv[0], ndv[1]), cvtpk(ndv[2], ndv[3]));
    }
    __syncthreads();
  }
}

extern "C" void kernel_launch(void* const* d_in, const int* in_sizes, int n_in,
                              void* d_out, int out_size, void* d_ws, size_t ws_size,
                              hipStream_t stream)
{
  const float* counts   = (const float*)d_in[0];
  const float* momentum = (const float*)d_in[1];
  const float* ke       = (const float*)d_in[2];
  const float* order    = (const float*)d_in[3];
  const float* W1 = (const float*)d_in[4];
  const float* b1 = (const float*)d_in[5];
  const float* W2 = (const float*)d_in[6];
  const float* b2 = (const float*)d_in[7];
  const float* W3 = (const float*)d_in[8];
  const float* b3 = (const float*)d_in[9];

  u16*   wsA = (u16*)d_ws;
  float* wsB = (float*)((char*)d_ws + 38 * 64 * 8 * sizeof(u16));  // +38912 B

  pack_weights<<<dim3(40), dim3(64), 0, stream>>>(W1, b1, W2, b2, W3, b3, wsA, wsB);
  fused_mlp<<<dim3(1728, 2), dim3(256), 0, stream>>>(counts, momentum, ke, order,
                                                     wsA, wsB, (float*)d_out);
}

// Round 4
// 297.935 us; speedup vs baseline: 1.3027x; 1.0371x over previous
//
#include <hip/hip_runtime.h>

typedef unsigned short u16;
typedef unsigned int   u32;
typedef __attribute__((ext_vector_type(8))) short bf16x8;
typedef __attribute__((ext_vector_type(4))) float f32x4;
typedef union { u32 w[4]; bf16x8 v; } bfpack;

#define NV 110592          // 48*48*48

#define OFF_A  0u
#define OFF_MM (96u*NV)
#define OFF_MK (384u*NV)
#define OFF_FM (480u*NV)
#define OFF_FK (516u*NV)

__device__ __forceinline__ u16 f2bf(float f) {
  u32 u = __float_as_uint(f);
  u += 0x7FFFu + ((u >> 16) & 1u);   // RNE
  return (u16)(u >> 16);
}
__device__ __forceinline__ u32 cvtpk(float a, float b) {
  u32 r; asm("v_cvt_pk_bf16_f32 %0, %1, %2" : "=v"(r) : "v"(a), "v"(b)); return r;
}
__device__ __forceinline__ float silu_f(float x) {
  float s = __builtin_amdgcn_rcpf(1.0f + __builtin_amdgcn_exp2f(-1.44269504089f * x));
  return x * s;
}
__device__ __forceinline__ float softplus_f(float x) {
  float e = __builtin_amdgcn_exp2f(-1.44269504089f * fabsf(x));
  return fmaxf(x, 0.0f) + 0.69314718056f * __builtin_amdgcn_logf(1.0f + e);
}
// channel-slot permutation making D-frags (groups of 4) == next B-frags (groups of 8)
__device__ __forceinline__ int chmap(int r, int m) {
  return ((r >> 1) << 5) + ((m >> 2) << 3) + ((r & 1) << 2) + (m & 3);
}

// ---------------- weight fragment packing (runs every launch; d_ws re-poisoned) ----
// wsA frags: [0..23]  A1 per face: idx = face*4 + rowtile   (rotation folded in)
//            [24..31] A2: idx = 24 + r*2 + t
//            [32..37] A3: idx = 32 + r*2 + t
// wsB: [0..15] b2 per-lane, [16..27] b3 per-lane
// K-slot map (face-invariant input layout):
//   k0..7  src counts     k8..10 src mom RAW   k11 ke  k12 order  k13 bias=1  k14..15 0
//   k16..23 dst counts    k24..26 dst mom RAW  k27 ke  k28 order  k29..31 0
__global__ void pack_weights(const float* __restrict__ W1, const float* __restrict__ b1,
                             const float* __restrict__ W2, const float* __restrict__ b2,
                             const float* __restrict__ W3, const float* __restrict__ b3,
                             u16* __restrict__ wsA, float* __restrict__ wsB)
{
  const int l  = threadIdx.x;       // 0..63
  const int m  = l & 15;
  const int hq = l >> 4;
  const int f  = blockIdx.x;

  if (f < 24) {                      // A1 for face
    const int face = f >> 2, r = f & 3;
    const int row  = chmap(r, m);
    const int   slot_tbl[6][3] = {{0,1,2},{0,1,2},{1,0,2},{1,0,2},{1,2,0},{1,2,0}};
    const float sign_tbl[6][3] = {{1,1,1},{-1,1,1},{1,1,1},{1,-1,1},{1,1,1},{1,1,-1}};
    #pragma unroll
    for (int j = 0; j < 8; ++j) {
      const int k = hq * 8 + j;
      float v;
      if      (k < 8)   v = W1[row * 26 + k];
      else if (k < 11)  { int cm = k - 8;  v = sign_tbl[face][cm] * W1[row * 26 + 8  + slot_tbl[face][cm]]; }
      else if (k == 11) v = W1[row * 26 + 11];
      else if (k == 12) v = W1[row * 26 + 12];
      else if (k == 13) v = b1[row];
      else if (k < 16)  v = 0.0f;
      else if (k < 24)  v = W1[row * 26 + 13 + (k - 16)];
      else if (k < 27)  { int cm = k - 24; v = sign_tbl[face][cm] * W1[row * 26 + 21 + slot_tbl[face][cm]]; }
      else if (k == 27) v = W1[row * 26 + 24];
      else if (k == 28) v = W1[row * 26 + 25];
      else              v = 0.0f;
      wsA[(f * 64 + l) * 8 + j] = f2bf(v);
    }
  } else if (f < 32) {               // A2
    const int r = (f - 24) >> 1, t = (f - 24) & 1;
    const int row = chmap(r, m);
    #pragma unroll
    for (int j = 0; j < 8; ++j) {
      const int k = t * 32 + hq * 8 + j;
      wsA[(f * 64 + l) * 8 + j] = f2bf(W2[row * 64 + k]);
    }
  } else if (f < 38) {               // A3 (rows >=44 zero)
    const int r = (f - 32) >> 1, t = (f - 32) & 1;
    const int row = r * 16 + m;
    #pragma unroll
    for (int j = 0; j < 8; ++j) {
      const int k = t * 32 + hq * 8 + j;
      float v = (row < 44) ? W3[row * 64 + k] : 0.0f;
      wsA[(f * 64 + l) * 8 + j] = f2bf(v);
    }
  } else if (f == 38) {              // b2 acc-init per lane
    #pragma unroll
    for (int s = 0; s < 16; ++s) {
      const int r = s >> 2, jj = s & 3;
      wsB[s * 64 + l] = b2[chmap(r, hq * 4 + jj)];
    }
  } else {                           // b3 acc-init per lane
    #pragma unroll
    for (int s = 0; s < 12; ++s) {
      const int r = s >> 2, jj = s & 3;
      const int o = r * 16 + hq * 4 + jj;
      wsB[(16 + s) * 64 + l] = (o < 44) ? b3[o] : 0.0f;
    }
  }
}

// ---------------- main fused kernel: LDS-free, barrier-free ----------------
// Each wave owns 16 voxels (N=16 cols). Lane (q,nn): B-frag K-slots q*8..q*8+7 for
// voxel v16. Loads go straight global->reg (quarter-coalesced 64B lines), packed
// with v_cvt_pk_bf16_f32. Next-face values + A1 frags prefetched into a second
// register set. No __syncthreads anywhere.
__global__ __launch_bounds__(256, 2) void fused_mlp(
    const float* __restrict__ counts, const float* __restrict__ momentum,
    const float* __restrict__ ke, const float* __restrict__ order,
    const u16* __restrict__ wsA, const float* __restrict__ wsB,
    float* __restrict__ out)
{
  const int tid = threadIdx.x;
  const int ln  = tid & 63;
  const int wv  = tid >> 6;
  const int q   = ln >> 4;
  const int nn  = ln & 15;
  const int b   = blockIdx.y;
  const int v16 = blockIdx.x * 64 + wv * 16 + nn;   // this lane's voxel (column)

  const int z  = v16 % 48;
  const int rr = v16 / 48;
  const int y  = rr % 48;
  const int x  = rr / 48;

  const bool isdst = (q >= 2);
  const bool qodd  = (q & 1);
  const float bias5 = (q == 1) ? 1.0f : 0.0f;
  const bool inval4 = isdst && (z == 47);
  const bool inval5 = isdst && (z == 0);

  // per-face load index for this lane (src lanes: own voxel; dst lanes: neighbor)
  int dvs[6];
  dvs[0] = isdst ? (v16 + ((x == 47) ? -108288 : 2304)) : v16;
  dvs[1] = isdst ? (v16 + ((x == 0)  ?  108288 : -2304)) : v16;
  dvs[2] = isdst ? (v16 + ((y == 47) ? -2256   : 48))    : v16;
  dvs[3] = isdst ? (v16 + ((y == 0)  ?  2256   : -48))   : v16;
  dvs[4] = (isdst && z != 47) ? v16 + 1 : v16;
  dvs[5] = (isdst && z != 0)  ? v16 - 1 : v16;

  // per-lane K-slot channel pointers
  const float* BP[8];
  #pragma unroll
  for (int j = 0; j < 8; ++j) {
    const float* p;
    if (!qodd) {
      p = counts + ((size_t)b * 8 + j) * NV;           // counts 0..7
    } else {
      const int c = 8 + j;                              // mom/ke/order/bias/pad
      if      (c < 11)  p = momentum + ((size_t)b * 3 + (c - 8)) * NV;
      else if (c == 11) p = ke    + (size_t)b * NV;
      else if (c == 12) p = order + (size_t)b * NV;
      else              p = ke    + (size_t)b * NV;     // dummy; const-overwritten
    }
    BP[j] = p;
  }

  // resident weights (unified VGPR/AGPR file absorbs these)
  const bf16x8* wsAf = (const bf16x8*)wsA;
  bf16x8 A2[4][2], A3[3][2];
  #pragma unroll
  for (int r = 0; r < 4; ++r)
    #pragma unroll
    for (int t = 0; t < 2; ++t) A2[r][t] = wsAf[(24 + r * 2 + t) * 64 + ln];
  #pragma unroll
  for (int r = 0; r < 3; ++r)
    #pragma unroll
    for (int t = 0; t < 2; ++t) A3[r][t] = wsAf[(32 + r * 2 + t) * 64 + ln];
  float b2v[16], b3v[12];
  #pragma unroll
  for (int s = 0; s < 16; ++s) b2v[s] = wsB[s * 64 + ln];
  #pragma unroll
  for (int s = 0; s < 12; ++s) b3v[s] = wsB[(16 + s) * 64 + ln];

  // per-lane output addressing: off walks +fsv per face
  u32 off[12], fsv[12];
  u32 spmask = 0, vmask = 0;
  #pragma unroll
  for (int r3 = 0; r3 < 3; ++r3) {
    #pragma unroll
    for (int jj = 0; jj < 4; ++jj) {
      const int slot = r3 * 4 + jj;
      const int o = r3 * 16 + q * 4 + jj;
      u32 c0 = 0, f0 = 0; bool sp = false, va = true;
      if (o < 3)       { c0 = OFF_FM + (u32)o * NV;        f0 = 3u * NV; }
      else if (o == 3) { c0 = OFF_FK;                      f0 = 1u * NV; sp = true; }
      else if (o < 12) { c0 = OFF_A  + (u32)(o - 4) * NV;  f0 = 8u * NV; sp = true; }
      else if (o < 36) { c0 = OFF_MM + (u32)(o - 12) * NV; f0 = 24u * NV; }
      else if (o < 44) { c0 = OFF_MK + (u32)(o - 36) * NV; f0 = 8u * NV; sp = true; }
      else va = false;
      off[slot] = c0 + (u32)(b * 6) * f0 + (u32)v16;
      fsv[slot] = f0;
      if (sp) spmask |= (1u << slot);
      if (va) vmask  |= (1u << slot);
    }
  }

  // prologue: face-0 values + A1
  float cur[8], nxt[8];
  bf16x8 A1c[4], A1n[4];
  #pragma unroll
  for (int j = 0; j < 8; ++j) cur[j] = BP[j][dvs[0]];
  cur[5] = qodd ? bias5 : cur[5];
  cur[6] = qodd ? 0.0f : cur[6];
  cur[7] = qodd ? 0.0f : cur[7];
  #pragma unroll
  for (int r = 0; r < 4; ++r) A1c[r] = wsAf[r * 64 + ln];

  #pragma unroll
  for (int f = 0; f < 6; ++f) {
    // issue-early prefetch of next face (values + A1 frags)
    if (f < 5) {
      #pragma unroll
      for (int j = 0; j < 8; ++j) nxt[j] = BP[j][dvs[f + 1]];
      #pragma unroll
      for (int r = 0; r < 4; ++r) A1n[r] = wsAf[((f + 1) * 4 + r) * 64 + ln];
    }

    // pack current face's B-fragment
    bfpack B1;
    B1.w[0] = cvtpk(cur[0], cur[1]);
    B1.w[1] = cvtpk(cur[2], cur[3]);
    B1.w[2] = cvtpk(cur[4], cur[5]);
    B1.w[3] = cvtpk(cur[6], cur[7]);

    const f32x4 zf = {0.0f, 0.0f, 0.0f, 0.0f};
    f32x4 acc1[4];
    #pragma unroll
    for (int r = 0; r < 4; ++r)
      acc1[r] = __builtin_amdgcn_mfma_f32_16x16x32_bf16(A1c[r], B1.v, zf, 0, 0, 0);

    bfpack B2p[2];
    #pragma unroll
    for (int t = 0; t < 2; ++t) {
      B2p[t].w[0] = cvtpk(silu_f(acc1[t*2][0]),   silu_f(acc1[t*2][1]));
      B2p[t].w[1] = cvtpk(silu_f(acc1[t*2][2]),   silu_f(acc1[t*2][3]));
      B2p[t].w[2] = cvtpk(silu_f(acc1[t*2+1][0]), silu_f(acc1[t*2+1][1]));
      B2p[t].w[3] = cvtpk(silu_f(acc1[t*2+1][2]), silu_f(acc1[t*2+1][3]));
    }

    f32x4 acc2[4];
    #pragma unroll
    for (int r = 0; r < 4; ++r) {
      f32x4 ci = {b2v[4*r+0], b2v[4*r+1], b2v[4*r+2], b2v[4*r+3]};
      acc2[r] = __builtin_amdgcn_mfma_f32_16x16x32_bf16(A2[r][0], B2p[0].v, ci, 0, 0, 0);
      acc2[r] = __builtin_amdgcn_mfma_f32_16x16x32_bf16(A2[r][1], B2p[1].v, acc2[r], 0, 0, 0);
    }

    bfpack B3p[2];
    #pragma unroll
    for (int t = 0; t < 2; ++t) {
      B3p[t].w[0] = cvtpk(silu_f(acc2[t*2][0]),   silu_f(acc2[t*2][1]));
      B3p[t].w[1] = cvtpk(silu_f(acc2[t*2][2]),   silu_f(acc2[t*2][3]));
      B3p[t].w[2] = cvtpk(silu_f(acc2[t*2+1][0]), silu_f(acc2[t*2+1][1]));
      B3p[t].w[3] = cvtpk(silu_f(acc2[t*2+1][2]), silu_f(acc2[t*2+1][3]));
    }

    f32x4 acc3[3];
    #pragma unroll
    for (int r = 0; r < 3; ++r) {
      f32x4 ci = {b3v[4*r+0], b3v[4*r+1], b3v[4*r+2], b3v[4*r+3]};
      acc3[r] = __builtin_amdgcn_mfma_f32_16x16x32_bf16(A3[r][0], B3p[0].v, ci, 0, 0, 0);
      acc3[r] = __builtin_amdgcn_mfma_f32_16x16x32_bf16(A3[r][1], B3p[1].v, acc3[r], 0, 0, 0);
    }

    // epilogue + stores; advance per-face channel-plane offsets
    #pragma unroll
    for (int r3 = 0; r3 < 3; ++r3) {
      #pragma unroll
      for (int jj = 0; jj < 4; ++jj) {
        const int slot = r3 * 4 + jj;
        float val = acc3[r3][jj];
        float res = ((spmask >> slot) & 1u) ? softplus_f(val) : val;
        if ((vmask >> slot) & 1u)
          out[off[slot]] = res;
        off[slot] += fsv[slot];
      }
    }

    // rotate prefetched next face into current (with const/validity fixups)
    if (f < 5) {
      const bool inv = ((f + 1) == 4) ? inval4 : (((f + 1) == 5) ? inval5 : false);
      #pragma unroll
      for (int j = 0; j < 8; ++j) nxt[j] = inv ? 0.0f : nxt[j];
      nxt[5] = qodd ? bias5 : nxt[5];
      nxt[6] = qodd ? 0.0f : nxt[6];
      nxt[7] = qodd ? 0.0f : nxt[7];
      #pragma unroll
      for (int j = 0; j < 8; ++j) cur[j] = nxt[j];
      #pragma unroll
      for (int r = 0; r < 4; ++r) A1c[r] = A1n[r];
    }
  }
}

extern "C" void kernel_launch(void* const* d_in, const int* in_sizes, int n_in,
                              void* d_out, int out_size, void* d_ws, size_t ws_size,
                              hipStream_t stream)
{
  const float* counts   = (const float*)d_in[0];
  const float* momentum = (const float*)d_in[1];
  const float* ke       = (const float*)d_in[2];
  const float* order    = (const float*)d_in[3];
  const float* W1 = (const float*)d_in[4];
  const float* b1 = (const float*)d_in[5];
  const float* W2 = (const float*)d_in[6];
  const float* b2 = (const float*)d_in[7];
  const float* W3 = (const float*)d_in[8];
  const float* b3 = (const float*)d_in[9];

  u16*   wsA = (u16*)d_ws;
  float* wsB = (float*)((char*)d_ws + 38 * 64 * 8 * sizeof(u16));  // +38912 B

  pack_weights<<<dim3(40), dim3(64), 0, stream>>>(W1, b1, W2, b2, W3, b3, wsA, wsB);
  fused_mlp<<<dim3(1728, 2), dim3(256), 0, stream>>>(counts, momentum, ke, order,
                                                     wsA, wsB, (float*)d_out);
}